// Round 3
// baseline (3090.287 us; speedup 1.0000x reference)
//
#include <hip/hip_runtime.h>

// GNN encoder + GRU message-passing decoder (fully-connected 32-node graph).
// ALL I/O float32 (reference dtypes are jnp.float32; harness contract:
// "float32 -> const float*"). R1/R2 NaNs were fp32 buffers misread as bf16.
//
// Shapes: B=16, N=32, E=992 (=32*31), IN_ENC=150, hidden=256, feat=128,
// T=25 decoder steps, dec feature = 3.
//
// Key restructure: edge MLP layer-1 on concat(x_send, x_rec) decomposes into
// per-node projections P = x @ w1[:128,:], Q = x @ w1[128:,:]  (67 MFLOP)
// instead of a 15872x256x256 GEMM (2.1 GFLOP). Layer-2 + edge->node mean are
// fused in edge_reduce_kernel (the hot loop: 520 MMAC / invocation).
//
// Scratch in static __device__ globals (no ws_size dependence, no
// hipGetSymbolAddress) -- kernels reference the symbols directly.

#define NJ 32
#define ROWS 512      // B*N
#define INENC 150
#define NH 256
#define NO 128
#define EH 256
#define EO 128
#define DECIN 3
#define TSTEPS 25

// Static device scratch. Fully rewritten before every read each call, so the
// harness's 0xAA re-poisoning of d_ws is irrelevant (d_ws unused).
__device__ float g_x[ROWS * NO];     // node features / GRU hidden state
__device__ float g_P[ROWS * EH];     // send-projection
__device__ float g_Q[ROWS * EH];     // rec-projection
__device__ float g_msg[ROWS * EO];   // edge->node mean message

// ---------------- generic row-MLP: g_x = relu(relu(in@w1+b1)@w2+b2) ----------
// SRC=0: input = `in` param [512, in_dim]; SRC=1: input = g_msg [512,128].
// w1: [in_dim, 256], w2: [256, 128]. grid = 512 rows, block = 256.
template <int SRC>
__global__ void mlp_kernel(const float* __restrict__ in, int in_dim,
                           const float* __restrict__ w1, const float* __restrict__ b1,
                           const float* __restrict__ w2, const float* __restrict__ b2) {
    __shared__ float s_in[NH];    // in_dim <= 256 (150 or 128)
    __shared__ float s_hid[NH];
    const int row = blockIdx.x;
    const int t = threadIdx.x;
    const float* rp = (SRC == 0) ? (in + (size_t)row * in_dim)
                                 : (g_msg + (size_t)row * EO);
    for (int k = t; k < in_dim; k += 256) s_in[k] = rp[k];
    __syncthreads();
    float acc = b1[t];
    for (int k = 0; k < in_dim; ++k) acc += s_in[k] * w1[k * NH + t];
    s_hid[t] = fmaxf(acc, 0.f);
    __syncthreads();
    if (t < EO) {
        float a2 = b2[t];
        #pragma unroll 4
        for (int k = 0; k < NH; ++k) a2 += s_hid[k] * w2[k * EO + t];
        g_x[(size_t)row * EO + t] = fmaxf(a2, 0.f);
    }
}

// ---------------- per-node projections for edge layer 1 ----------------
// P[row][j] = sum_k x[row][k]*w1[k][j], Q[row][j] = sum_k x[row][k]*w1[128+k][j]
// w1: [256,256]. grid=512, block=256.
__global__ void pq_kernel(const float* __restrict__ w1) {
    __shared__ float s_x[NO];
    const int row = blockIdx.x;
    const int t = threadIdx.x;
    if (t < NO) s_x[t] = g_x[(size_t)row * NO + t];
    __syncthreads();
    float p = 0.f, q = 0.f;
    #pragma unroll 4
    for (int k = 0; k < NO; ++k) {
        float xv = s_x[k];
        p += xv * w1[k * EH + t];
        q += xv * w1[(NO + k) * EH + t];
    }
    g_P[(size_t)row * EH + t] = p;
    g_Q[(size_t)row * EH + t] = q;
}

// ---------------- fused edge layer-2 + edge->node mean ----------------
// msg[b,r] = (1/31) * sum_{s != r} relu( relu(P[b,s]+Q[b,r]+b1) @ w2 + b2 )
// grid = 512 (b*32+r), block = 256 (threads split the k-dim in halves)
__global__ void edge_reduce_kernel(const float* __restrict__ b1, const float* __restrict__ w2,
                                   const float* __restrict__ b2) {
    const int b = blockIdx.x >> 5;
    const int r = blockIdx.x & 31;
    const int t = threadIdx.x;          // 256
    const int j = t & (EO - 1);         // output col
    const int half = t >> 7;            // which half of k-dim
    __shared__ float s_qb[EH];
    __shared__ float s_h1[EH];
    __shared__ float s_part[2 * EO];
    s_qb[t] = g_Q[((size_t)b * NJ + r) * EH + t] + b1[t];
    const float b2j = (t < EO) ? b2[t] : 0.f;
    float acc = 0.f;
    __syncthreads();
    const int k0 = half * (EH / 2);
    for (int s = 0; s < NJ; ++s) {
        if (s == r) continue;           // block-uniform: r is per-block
        s_h1[t] = fmaxf(g_P[((size_t)b * NJ + s) * EH + t] + s_qb[t], 0.f);
        __syncthreads();
        float part = 0.f;
        #pragma unroll 8
        for (int k = 0; k < EH / 2; ++k)
            part += s_h1[k0 + k] * w2[(k0 + k) * EO + j];
        s_part[t] = part;
        __syncthreads();
        if (t < EO) acc += fmaxf(s_part[t] + s_part[t + EO] + b2j, 0.f);
        __syncthreads();                // protect s_h1/s_part rewrite next iter
    }
    if (t < EO) g_msg[((size_t)b * NJ + r) * EO + t] = acc * (1.f / 31.f);
}

// ---------------- GRU-style gated update ----------------
// grid = 512 rows, block = 128. Updates g_x (=h) in place; writes f32 outputs.
__global__ void gru_kernel(const float* __restrict__ dec_in,
                           const float* __restrict__ w_hr, const float* __restrict__ w_hi,
                           const float* __restrict__ w_hn,
                           const float* __restrict__ w_ir, const float* __restrict__ b_ir,
                           const float* __restrict__ w_ii, const float* __restrict__ b_ii,
                           const float* __restrict__ w_in, const float* __restrict__ b_in,
                           float* __restrict__ out, float* __restrict__ out2) {
    const int row = blockIdx.x;
    const int j = threadIdx.x;          // 128
    __shared__ float s_m[EO];
    __shared__ float s_h[NO];
    __shared__ float s_i[DECIN];
    s_m[j] = g_msg[(size_t)row * EO + j];
    s_h[j] = g_x[(size_t)row * NO + j];
    if (j < DECIN) s_i[j] = dec_in[(size_t)row * DECIN + j];
    __syncthreads();
    float rs = b_ir[j];
    float is = b_ii[j];
    float ns = b_in[j];
    float hn = 0.f;
    #pragma unroll 4
    for (int k = 0; k < EO; ++k) {
        float m = s_m[k];
        rs += m * w_ir[k * NO + j];
        is += m * w_ii[k * NO + j];
        ns += m * w_in[k * NO + j];
    }
    #pragma unroll
    for (int k = 0; k < DECIN; ++k) {
        float v = s_i[k];
        rs += v * w_ir[(EO + k) * NO + j];
        is += v * w_ii[(EO + k) * NO + j];
        ns += v * w_in[(EO + k) * NO + j];
    }
    #pragma unroll 4
    for (int k = 0; k < NO; ++k) {
        float hv = s_h[k];
        rs += hv * w_hr[k * NO + j];
        is += hv * w_hi[k * NO + j];
        hn += hv * w_hn[k * NO + j];
    }
    const float r = 1.f / (1.f + __expf(-rs));
    const float i = 1.f / (1.f + __expf(-is));
    const float n = tanhf(ns + r * hn);
    const float hnew = (1.f - i) * n + i * s_h[j];
    g_x[(size_t)row * NO + j] = hnew;
    out[(size_t)row * NO + j] = hnew;
    if (out2) out2[(size_t)row * NO + j] = hnew;
}

extern "C" void kernel_launch(void* const* d_in, const int* in_sizes, int n_in,
                              void* d_out, int out_size, void* d_ws, size_t ws_size,
                              hipStream_t stream) {
    const float* enc_in = (const float*)d_in[0];
    const float* dec_in = (const float*)d_in[1];
    // d_in[2], d_in[3] = R, S one-hot incidence: fully-connected, not needed.
    const float* enc_w1 = (const float*)d_in[4];
    const float* enc_b1 = (const float*)d_in[5];
    const float* enc_w2 = (const float*)d_in[6];
    const float* enc_b2 = (const float*)d_in[7];
    const float* pe_w1 = (const float*)d_in[8];
    const float* pe_b1 = (const float*)d_in[9];
    const float* pe_w2 = (const float*)d_in[10];
    const float* pe_b2 = (const float*)d_in[11];
    const float* pn_w1 = (const float*)d_in[12];
    const float* pn_b1 = (const float*)d_in[13];
    const float* pn_w2 = (const float*)d_in[14];
    const float* pn_b2 = (const float*)d_in[15];
    const float* de_w1 = (const float*)d_in[16];
    const float* de_b1 = (const float*)d_in[17];
    const float* de_w2 = (const float*)d_in[18];
    const float* de_b2 = (const float*)d_in[19];
    const float* w_hr = (const float*)d_in[20];
    const float* w_hi = (const float*)d_in[21];
    const float* w_hn = (const float*)d_in[22];
    const float* w_ir = (const float*)d_in[23];
    const float* b_ir = (const float*)d_in[24];
    const float* w_ii = (const float*)d_in[25];
    const float* b_ii = (const float*)d_in[26];
    const float* w_in = (const float*)d_in[27];
    const float* b_in = (const float*)d_in[28];
    (void)d_ws; (void)ws_size; (void)in_sizes; (void)n_in;

    // ---- encoder MLP: g_x = mlp(encoder_input) ----
    mlp_kernel<0><<<ROWS, 256, 0, stream>>>(enc_in, INENC, enc_w1, enc_b1, enc_w2, enc_b2);

    // ---- 2 message-passing rounds ----
    for (int p = 0; p < 2; ++p) {
        pq_kernel<<<ROWS, 256, 0, stream>>>(pe_w1);
        edge_reduce_kernel<<<ROWS, 256, 0, stream>>>(pe_b1, pe_w2, pe_b2);
        mlp_kernel<1><<<ROWS, 256, 0, stream>>>(nullptr, EO, pn_w1, pn_b1, pn_w2, pn_b2);
    }

    // ---- GRU decoder: 25 steps ----
    float* out = (float*)d_out;
    for (int t = 0; t < TSTEPS; ++t) {
        pq_kernel<<<ROWS, 256, 0, stream>>>(de_w1);
        edge_reduce_kernel<<<ROWS, 256, 0, stream>>>(de_b1, de_w2, de_b2);
        float* o1 = out + (size_t)t * ROWS * NO;
        float* o2 = (t == TSTEPS - 1) ? (out + (size_t)TSTEPS * ROWS * NO) : nullptr;
        gru_kernel<<<ROWS, 128, 0, stream>>>(dec_in + (size_t)t * ROWS * DECIN,
                                             w_hr, w_hi, w_hn, w_ir, b_ir, w_ii, b_ii,
                                             w_in, b_in, o1, o2);
    }
}

// Round 4
// 1105.468 us; speedup vs baseline: 2.7955x; 2.7955x over previous
//
#include <hip/hip_runtime.h>

// GNN encoder + GRU message-passing decoder (fully-connected 32-node graph).
// ALL I/O float32. Internal: fp32 everywhere EXCEPT the edge-MLP layer-2 GEMM,
// which runs as bf16 MFMA (fp32 accumulate) -- it was 91% of runtime in fp32.
//
// R4 change: edge_reduce (103 us/dispatch, VALUBusy 28%, MFMA 0) replaced by
// edge_mfma_kernel: per block = one (batch, r-pair), H1 tile [64x256] bf16 in
// LDS (+8 pad/row -> 2-way bank alias = free), w2 pre-transposed to bf16
// w2T[j][k] once per launch, 16x16x32 bf16 MFMA, relu+sum epilogue via
// shfl_xor + LDS. Diagonal s==r: H1 row zeroed (contributes exactly
// relu(b2[j])), subtracted in the epilogue -- exact.

#define NJ 32
#define ROWS 512      // B*N
#define INENC 150
#define NH 256
#define NO 128
#define EH 256
#define EO 128
#define DECIN 3
#define TSTEPS 25
#define LDK 264       // H1 LDS row stride in bf16 elems (256 + 8 pad)

typedef __attribute__((ext_vector_type(8))) short short8;
typedef __attribute__((ext_vector_type(4))) float f32x4;

// Static device scratch (fully rewritten before every read each call).
__device__ float g_x[ROWS * NO];     // node features / GRU hidden state
__device__ float g_P[ROWS * EH];     // send-projection
__device__ float g_Q[ROWS * EH];     // rec-projection
__device__ float g_msg[ROWS * EO];   // edge->node mean message
__device__ __align__(16) short g_pe_w2T[EO * EH];  // pe_w2 transposed, bf16
__device__ __align__(16) short g_de_w2T[EO * EH];  // de_w2 transposed, bf16

__device__ __forceinline__ short f2bf(float x) {   // RNE float->bf16 bits
    unsigned u = __float_as_uint(x);
    return (short)((u + 0x7FFFu + ((u >> 16) & 1u)) >> 16);
}

// ---------------- w2 -> bf16 transposed copies (once per launch) -------------
// grid 256 x 256: idx < 32768 -> pe, else de. out[j*256+k] = bf16(w2[k*128+j])
__global__ void convert_w2_kernel(const float* __restrict__ pe_w2,
                                  const float* __restrict__ de_w2) {
    const int idx = blockIdx.x * 256 + threadIdx.x;
    const float* src = (idx < EO * EH) ? pe_w2 : de_w2;
    short* dst = (idx < EO * EH) ? g_pe_w2T : g_de_w2T;
    const int o = idx & (EO * EH - 1);
    const int j = o >> 8;          // 0..127
    const int k = o & 255;         // 0..255
    dst[o] = f2bf(src[k * EO + j]);
}

// ---------------- generic row-MLP: g_x = relu(relu(in@w1+b1)@w2+b2) ----------
template <int SRC>
__global__ void mlp_kernel(const float* __restrict__ in, int in_dim,
                           const float* __restrict__ w1, const float* __restrict__ b1,
                           const float* __restrict__ w2, const float* __restrict__ b2) {
    __shared__ float s_in[NH];
    __shared__ float s_hid[NH];
    const int row = blockIdx.x;
    const int t = threadIdx.x;
    const float* rp = (SRC == 0) ? (in + (size_t)row * in_dim)
                                 : (g_msg + (size_t)row * EO);
    for (int k = t; k < in_dim; k += 256) s_in[k] = rp[k];
    __syncthreads();
    float acc = b1[t];
    for (int k = 0; k < in_dim; ++k) acc += s_in[k] * w1[k * NH + t];
    s_hid[t] = fmaxf(acc, 0.f);
    __syncthreads();
    if (t < EO) {
        float a2 = b2[t];
        #pragma unroll 4
        for (int k = 0; k < NH; ++k) a2 += s_hid[k] * w2[k * EO + t];
        g_x[(size_t)row * EO + t] = fmaxf(a2, 0.f);
    }
}

// ---------------- per-node projections for edge layer 1 ----------------
__global__ void pq_kernel(const float* __restrict__ w1) {
    __shared__ float s_x[NO];
    const int row = blockIdx.x;
    const int t = threadIdx.x;
    if (t < NO) s_x[t] = g_x[(size_t)row * NO + t];
    __syncthreads();
    float p = 0.f, q = 0.f;
    #pragma unroll 4
    for (int k = 0; k < NO; ++k) {
        float xv = s_x[k];
        p += xv * w1[k * EH + t];
        q += xv * w1[(NO + k) * EH + t];
    }
    g_P[(size_t)row * EH + t] = p;
    g_Q[(size_t)row * EH + t] = q;
}

// ---------------- MFMA edge layer-2 + relu + edge->node mean ----------------
// Block = one (b, r-pair): rows 64 = {rp in 0..1} x {s in 0..31}, K=256, N=128.
// msg[b,r,j] = (sum_{s} relu(H1[s]@w2[:,j] + b2[j]) - relu(b2[j])) / 31,
// with H1[s==r] zeroed. grid = 256 (b*16 + rq), block = 256 (4 waves).
template <int WHICH>
__global__ void edge_mfma_kernel(const float* __restrict__ b1,
                                 const float* __restrict__ b2) {
    const short* __restrict__ w2T = (WHICH == 0) ? g_pe_w2T : g_de_w2T;
    const int b = blockIdx.x >> 4;
    const int rq = blockIdx.x & 15;
    const int t = threadIdx.x;
    const int wave = t >> 6;
    const int lane = t & 63;
    const int m = lane & 15;
    const int quad = lane >> 4;

    __shared__ __align__(16) short s_h1[64 * LDK];   // 33 KB
    __shared__ float s_red[4][EO];                   // 2 KB

    // ---- phase 1: H1[row][k] = bf16(relu(P[b,s,k]+Q[b,r,k]+b1[k])), diag=0
    {
        const int row = t >> 2;             // 0..63
        const int kbase = (t & 3) * 64;     // 4 threads per row
        const int rp = row >> 5;
        const int s = row & 31;
        const int r = rq * 2 + rp;
        const float* Pp = g_P + ((size_t)b * NJ + s) * EH;
        const float* Qp = g_Q + ((size_t)b * NJ + r) * EH;
        const bool diag = (s == r);
        for (int k8 = 0; k8 < 64; k8 += 8) {
            short8 pack;
            #pragma unroll
            for (int i = 0; i < 8; ++i) {
                const int k = kbase + k8 + i;
                float h = fmaxf(Pp[k] + Qp[k] + b1[k], 0.f);
                pack[i] = diag ? (short)0 : f2bf(h);
            }
            *(short8*)(&s_h1[row * LDK + kbase + k8]) = pack;
        }
    }
    __syncthreads();

    // ---- phase 2: per-wave [16 x 256] @ [256 x 128] MFMA
    f32x4 acc[8];
    #pragma unroll
    for (int jt = 0; jt < 8; ++jt) acc[jt] = (f32x4)(0.f);
    const int row0 = wave * 16;
    #pragma unroll
    for (int kk = 0; kk < 8; ++kk) {
        const short8 av = *(const short8*)(&s_h1[(row0 + m) * LDK + kk * 32 + quad * 8]);
        #pragma unroll
        for (int jt = 0; jt < 8; ++jt) {
            const short8 bv = *(const short8*)(&w2T[(jt * 16 + m) * EH + kk * 32 + quad * 8]);
            acc[jt] = __builtin_amdgcn_mfma_f32_16x16x32_bf16(av, bv, acc[jt], 0, 0, 0);
        }
    }

    // ---- epilogue: relu(acc + b2) summed over the wave's 16 s-rows
    // D layout: col j = lane&15, row s = quad*4 + reg
    #pragma unroll
    for (int jt = 0; jt < 8; ++jt) {
        const float b2j = b2[jt * 16 + m];
        float p = 0.f;
        #pragma unroll
        for (int i = 0; i < 4; ++i) p += fmaxf(acc[jt][i] + b2j, 0.f);
        p += __shfl_xor(p, 16);
        p += __shfl_xor(p, 32);
        if (lane < 16) s_red[wave][jt * 16 + lane] = p;
    }
    __syncthreads();

    // ---- combine wave pairs, subtract zeroed-diag contribution relu(b2[j])
    {
        const int rp = t >> 7;
        const int j = t & 127;
        const float v = (s_red[2 * rp][j] + s_red[2 * rp + 1][j] - fmaxf(b2[j], 0.f))
                        * (1.f / 31.f);
        g_msg[((size_t)b * NJ + rq * 2 + rp) * EO + j] = v;
    }
}

// ---------------- GRU-style gated update ----------------
__global__ void gru_kernel(const float* __restrict__ dec_in,
                           const float* __restrict__ w_hr, const float* __restrict__ w_hi,
                           const float* __restrict__ w_hn,
                           const float* __restrict__ w_ir, const float* __restrict__ b_ir,
                           const float* __restrict__ w_ii, const float* __restrict__ b_ii,
                           const float* __restrict__ w_in, const float* __restrict__ b_in,
                           float* __restrict__ out, float* __restrict__ out2) {
    const int row = blockIdx.x;
    const int j = threadIdx.x;          // 128
    __shared__ float s_m[EO];
    __shared__ float s_h[NO];
    __shared__ float s_i[DECIN];
    s_m[j] = g_msg[(size_t)row * EO + j];
    s_h[j] = g_x[(size_t)row * NO + j];
    if (j < DECIN) s_i[j] = dec_in[(size_t)row * DECIN + j];
    __syncthreads();
    float rs = b_ir[j];
    float is = b_ii[j];
    float ns = b_in[j];
    float hn = 0.f;
    #pragma unroll 4
    for (int k = 0; k < EO; ++k) {
        float mm = s_m[k];
        rs += mm * w_ir[k * NO + j];
        is += mm * w_ii[k * NO + j];
        ns += mm * w_in[k * NO + j];
    }
    #pragma unroll
    for (int k = 0; k < DECIN; ++k) {
        float v = s_i[k];
        rs += v * w_ir[(EO + k) * NO + j];
        is += v * w_ii[(EO + k) * NO + j];
        ns += v * w_in[(EO + k) * NO + j];
    }
    #pragma unroll 4
    for (int k = 0; k < NO; ++k) {
        float hv = s_h[k];
        rs += hv * w_hr[k * NO + j];
        is += hv * w_hi[k * NO + j];
        hn += hv * w_hn[k * NO + j];
    }
    const float r = 1.f / (1.f + __expf(-rs));
    const float i = 1.f / (1.f + __expf(-is));
    const float n = tanhf(ns + r * hn);
    const float hnew = (1.f - i) * n + i * s_h[j];
    g_x[(size_t)row * NO + j] = hnew;
    out[(size_t)row * NO + j] = hnew;
    if (out2) out2[(size_t)row * NO + j] = hnew;
}

extern "C" void kernel_launch(void* const* d_in, const int* in_sizes, int n_in,
                              void* d_out, int out_size, void* d_ws, size_t ws_size,
                              hipStream_t stream) {
    const float* enc_in = (const float*)d_in[0];
    const float* dec_in = (const float*)d_in[1];
    // d_in[2], d_in[3] = R, S one-hot incidence: fully-connected, not needed.
    const float* enc_w1 = (const float*)d_in[4];
    const float* enc_b1 = (const float*)d_in[5];
    const float* enc_w2 = (const float*)d_in[6];
    const float* enc_b2 = (const float*)d_in[7];
    const float* pe_w1 = (const float*)d_in[8];
    const float* pe_b1 = (const float*)d_in[9];
    const float* pe_w2 = (const float*)d_in[10];
    const float* pe_b2 = (const float*)d_in[11];
    const float* pn_w1 = (const float*)d_in[12];
    const float* pn_b1 = (const float*)d_in[13];
    const float* pn_w2 = (const float*)d_in[14];
    const float* pn_b2 = (const float*)d_in[15];
    const float* de_w1 = (const float*)d_in[16];
    const float* de_b1 = (const float*)d_in[17];
    const float* de_w2 = (const float*)d_in[18];
    const float* de_b2 = (const float*)d_in[19];
    const float* w_hr = (const float*)d_in[20];
    const float* w_hi = (const float*)d_in[21];
    const float* w_hn = (const float*)d_in[22];
    const float* w_ir = (const float*)d_in[23];
    const float* b_ir = (const float*)d_in[24];
    const float* w_ii = (const float*)d_in[25];
    const float* b_ii = (const float*)d_in[26];
    const float* w_in = (const float*)d_in[27];
    const float* b_in = (const float*)d_in[28];
    (void)d_ws; (void)ws_size; (void)in_sizes; (void)n_in;

    // ---- bf16 transposed w2 copies ----
    convert_w2_kernel<<<256, 256, 0, stream>>>(pe_w2, de_w2);

    // ---- encoder MLP: g_x = mlp(encoder_input) ----
    mlp_kernel<0><<<ROWS, 256, 0, stream>>>(enc_in, INENC, enc_w1, enc_b1, enc_w2, enc_b2);

    // ---- 2 message-passing rounds ----
    for (int p = 0; p < 2; ++p) {
        pq_kernel<<<ROWS, 256, 0, stream>>>(pe_w1);
        edge_mfma_kernel<0><<<256, 256, 0, stream>>>(pe_b1, pe_b2);
        mlp_kernel<1><<<ROWS, 256, 0, stream>>>(nullptr, EO, pn_w1, pn_b1, pn_w2, pn_b2);
    }

    // ---- GRU decoder: 25 steps ----
    float* out = (float*)d_out;
    for (int t = 0; t < TSTEPS; ++t) {
        pq_kernel<<<ROWS, 256, 0, stream>>>(de_w1);
        edge_mfma_kernel<1><<<256, 256, 0, stream>>>(de_b1, de_b2);
        float* o1 = out + (size_t)t * ROWS * NO;
        float* o2 = (t == TSTEPS - 1) ? (out + (size_t)TSTEPS * ROWS * NO) : nullptr;
        gru_kernel<<<ROWS, 128, 0, stream>>>(dec_in + (size_t)t * ROWS * DECIN,
                                             w_hr, w_hi, w_hn, w_ir, b_ir, w_ii, b_ii,
                                             w_in, b_in, o1, o2);
    }
}